// Round 8
// baseline (749.369 us; speedup 1.0000x reference)
//
#include <hip/hip_runtime.h>

#define NN 50000
#define EE 800000
#define RR 16
#define BBASES 8
#define SLOPE 0.01f
#define BCAP 16          // per-(dst,rel) slot capacity; Poisson(1): P(>=16)*800K ~ 1e-8
#define NT 16            // nodes per layer-block
#define SLICE 16384      // 128*128 elems per W slice
#define LSTRIDE (17 * SLICE)

typedef __attribute__((ext_vector_type(8))) short short8;
typedef __attribute__((ext_vector_type(4))) float f32x4;

static __device__ __forceinline__ ushort f2b(float f) {
    unsigned u = __float_as_uint(f);
    unsigned r = (u + 0x7FFF + ((u >> 16) & 1)) >> 16;
    return (ushort)r;
}
static __device__ __forceinline__ float b2f(ushort h) {
    return __uint_as_float(((unsigned)h) << 16);
}

// ---------------- x (f32) -> bf16 ----------------
__global__ __launch_bounds__(256) void k_cvt_x(
    const float* __restrict__ x, ushort* __restrict__ xb, long n4)
{
    for (long t = (long)blockIdx.x * blockDim.x + threadIdx.x; t < n4;
         t += (long)gridDim.x * blockDim.x) {
        float4 v = reinterpret_cast<const float4*>(x)[t];
        ushort4 o;
        o.x = f2b(v.x); o.y = f2b(v.y); o.z = f2b(v.z); o.w = f2b(v.w);
        reinterpret_cast<ushort4*>(xb)[t] = o;
    }
}

// ---------------- prep: stacked Wt (both layers, 17 slices each) + zero cursor + zero y1 ----
// Wt[l][r][n*128+k] = bf16( sum_b coeff_l[r,b] * basis_l[b][k*128+n] ), slice 16 = wloop^T
__global__ __launch_bounds__(256) void k_prep(
    const float* __restrict__ coeff1, const float* __restrict__ basis1,
    const float* __restrict__ coeff2, const float* __restrict__ basis2,
    const float* __restrict__ wloop1, const float* __restrict__ wloop2,
    ushort* __restrict__ Wt, int* __restrict__ curNR, float* __restrict__ y1)
{
    const int WTN = 2 * RR * SLICE;      // 524288
    const int WLN = 2 * SLICE;           // 32768
    const long total = WTN + WLN + (long)NN * RR + 128;
    for (long t = (long)blockIdx.x * blockDim.x + threadIdx.x; t < total;
         t += (long)gridDim.x * blockDim.x) {
        if (t < WTN) {
            int l = (int)(t >> 18);
            int rem = (int)(t & 262143);
            int r = rem >> 14;
            int kn = rem & 16383;
            int k = kn >> 7, n = kn & 127;
            const float* cf = l ? coeff2 : coeff1;
            const float* bs = l ? basis2 : basis1;
            float s = 0.f;
#pragma unroll
            for (int b = 0; b < BBASES; ++b)
                s += cf[r * BBASES + b] * bs[(long)b * SLICE + kn];
            Wt[(long)l * LSTRIDE + (long)r * SLICE + n * 128 + k] = f2b(s);
        } else if (t < WTN + WLN) {
            int j = (int)(t - WTN);
            int l = j >> 14;
            int kn = j & 16383;
            int k = kn >> 7, n = kn & 127;
            const float* wl = l ? wloop2 : wloop1;
            Wt[(long)l * LSTRIDE + 16 * SLICE + n * 128 + k] = f2b(wl[kn]);
        } else if (t < WTN + WLN + (long)NN * RR) {
            curNR[(int)(t - WTN - WLN)] = 0;
        } else {
            y1[(int)(t - WTN - WLN - (long)NN * RR)] = 0.f;
        }
    }
}

// ---------------- bucket edges by (dst, rel) ----------------
__global__ __launch_bounds__(256) void k_bucket(
    const int* __restrict__ src, const int* __restrict__ dst,
    const int* __restrict__ etype, int* __restrict__ curNR,
    int* __restrict__ bslot)
{
    for (long t = (long)blockIdx.x * blockDim.x + threadIdx.x; t < EE;
         t += (long)gridDim.x * blockDim.x) {
        int idx = dst[t] * RR + etype[t];
        int pos = atomicAdd(curNR + idx, 1);
        if (pos < BCAP)
            bslot[(size_t)idx * BCAP + pos] = src[t];
    }
}

// ---------------- fused layer: gather edge-sums into LDS A-tile, K=2176 MFMA ----------------
// mode 1: hbout = bf16(leakyrelu(C + bias))      (layer 1)
// mode 2: zout  = dot(C + bias, wagg) + bagg     (layer 2)
__global__ __launch_bounds__(512, 4) void k_layer(
    const ushort* __restrict__ Ain,   // [NN][128] bf16 node features
    const ushort* __restrict__ Bt,    // [17][128col][128k] bf16 stacked (slice16 = wloop^T)
    const int* __restrict__ bcnt,     // [NN*16]
    const int* __restrict__ bslot,    // [NN*16][BCAP]
    const float* __restrict__ bias,
    ushort* __restrict__ hbout,
    const float* __restrict__ wagg, const float* __restrict__ bagg,
    float* __restrict__ zout, int mode)
{
    __shared__ ushort As[NT * 2048];  // 64 KB, row = 4096 B = 256 x 16B chunks, XOR-swizzled
    int tid = threadIdx.x;
    int wid = tid >> 6, lane = tid & 63;
    int node0 = blockIdx.x * NT;

    // ---------- gather phase: wave w handles local nodes w and w+8 ----------
#pragma unroll
    for (int rep = 0; rep < 2; ++rep) {
        int n = wid + rep * 8;
        int gn = node0 + n;
        const int* cbase = bcnt + gn * RR;
        const int* sbase = bslot + (size_t)gn * (RR * BCAP);
        int cvec = (lane < RR) ? min(cbase[lane], BCAP) : 0;
        int sl01 = (lane < 2 * RR) ? sbase[(lane >> 1) * BCAP + (lane & 1)] : 0;
#pragma unroll
        for (int r = 0; r < RR; ++r) {
            int c = __shfl(cvec, r);
            int s0 = __shfl(sl01, 2 * r);
            int s1 = __shfl(sl01, 2 * r + 1);
            s0 = ((unsigned)s0 < NN) ? s0 : 0;   // clamp (uninit slots are garbage)
            s1 = ((unsigned)s1 < NN) ? s1 : 0;
            unsigned u0 = *reinterpret_cast<const unsigned*>(Ain + (size_t)s0 * 128 + lane * 2);
            unsigned u1 = *reinterpret_cast<const unsigned*>(Ain + (size_t)s1 * 128 + lane * 2);
            float ax = 0.f, ay = 0.f;
            if (c >= 1) { ax += b2f((ushort)(u0 & 0xFFFF)); ay += b2f((ushort)(u0 >> 16)); }
            if (c >= 2) { ax += b2f((ushort)(u1 & 0xFFFF)); ay += b2f((ushort)(u1 >> 16)); }
            for (int i = 2; i < c; ++i) {        // rare tail (Poisson(1))
                int s = sbase[r * BCAP + i];
                s = ((unsigned)s < NN) ? s : 0;
                unsigned u = *reinterpret_cast<const unsigned*>(Ain + (size_t)s * 128 + lane * 2);
                ax += b2f((ushort)(u & 0xFFFF)); ay += b2f((ushort)(u >> 16));
            }
            unsigned pk = (unsigned)f2b(ax) | ((unsigned)f2b(ay) << 16);
            int chunk = r * 16 + (lane >> 2);
            int byteoff = n * 4096 + ((chunk ^ (n & 7)) << 4) + (lane & 3) * 4;
            *reinterpret_cast<unsigned*>(reinterpret_cast<char*>(As) + byteoff) = pk;
        }
    }
    __syncthreads();

    // ---------- GEMM phase: wave owns 16-col quadrant, K = 17*128 ----------
    int lr = lane & 15, lk = lane >> 4;
    int colg = wid * 16 + lr;
    f32x4 acc = (f32x4){0.f, 0.f, 0.f, 0.f};
    const ushort* bcol = Bt + (size_t)colg * 128;

#pragma unroll 8
    for (int s = 0; s < 64; ++s) {               // slices 0..15 from LDS
        int chunk = s * 4 + lk;
        short8 a = *reinterpret_cast<const short8*>(
            reinterpret_cast<const char*>(As) + lr * 4096 + ((chunk ^ (lr & 7)) << 4));
        short8 b = *reinterpret_cast<const short8*>(
            bcol + (s >> 2) * SLICE + (s & 3) * 32 + lk * 8);
        acc = __builtin_amdgcn_mfma_f32_16x16x32_bf16(a, b, acc, 0, 0, 0);
    }
    {   // self slice (16) with A straight from global
        const ushort* arow = Ain + (size_t)(node0 + lr) * 128;
#pragma unroll
        for (int s = 0; s < 4; ++s) {
            short8 a = *reinterpret_cast<const short8*>(arow + s * 32 + lk * 8);
            short8 b = *reinterpret_cast<const short8*>(
                bcol + 16 * SLICE + s * 32 + lk * 8);
            acc = __builtin_amdgcn_mfma_f32_16x16x32_bf16(a, b, acc, 0, 0, 0);
        }
    }

    if (mode == 1) {
#pragma unroll
        for (int j = 0; j < 4; ++j) {
            int row = (lane >> 4) * 4 + j;
            float v = acc[j] + bias[colg];
            v = v >= 0.f ? v : SLOPE * v;
            hbout[(size_t)(node0 + row) * 128 + colg] = f2b(v);
        }
    } else {
        __syncthreads();                          // done with A-tile; reuse LDS
        float* Ctmp = reinterpret_cast<float*>(As);   // [16][132] padded
#pragma unroll
        for (int j = 0; j < 4; ++j) {
            int row = (lane >> 4) * 4 + j;
            Ctmp[row * 132 + colg] = acc[j] + bias[colg];
        }
        __syncthreads();
        if (wid == 0) {
            int row = lane >> 2, seg = lane & 3;
            float s = 0.f;
            for (int c = seg * 32; c < seg * 32 + 32; ++c)
                s += Ctmp[row * 132 + c] * wagg[c];
            s += __shfl_xor(s, 1);
            s += __shfl_xor(s, 2);
            if (seg == 0) zout[node0 + row] = s + bagg[0];
        }
    }
}

// ---------------- y1raw[j] = sum_n z[n]*wd1[n,j]  (j<100) ----------------
__global__ __launch_bounds__(256) void k_dense1(
    const float* __restrict__ z, const float* __restrict__ wd1,
    float* __restrict__ y1raw)
{
    int j = threadIdx.x & 127;
    int g = threadIdx.x >> 7;
    int rows_per_block = (NN + gridDim.x - 1) / gridDim.x;
    int n0 = blockIdx.x * rows_per_block;
    int n1 = min(NN, n0 + rows_per_block);
    if (j >= 100) return;
    float acc = 0.f;
    for (int n = n0 + g; n < n1; n += 2)
        acc += z[n] * wd1[(long)n * 100 + j];
    atomicAdd(y1raw + j, acc);
}

// ---------------- final tiny MLP head ----------------
__global__ __launch_bounds__(128) void k_final(
    const float* __restrict__ y1raw, const float* __restrict__ bd1,
    const float* __restrict__ wd2, const float* __restrict__ bd2,
    const float* __restrict__ wd3, const float* __restrict__ bd3,
    float* __restrict__ out)
{
    __shared__ float t1[100], t2[20];
    int t = threadIdx.x;
    if (t < 100) t1[t] = y1raw[t] + bd1[t];
    __syncthreads();
    if (t < 20) {
        float s = bd2[t];
        for (int j = 0; j < 100; ++j) s += t1[j] * wd2[j * 20 + t];
        t2[t] = s >= 0.f ? s : SLOPE * s;
    }
    __syncthreads();
    if (t < 10) {
        float s = bd3[t];
        for (int k = 0; k < 20; ++k) s += t2[k] * wd3[k * 10 + t];
        out[t] = s;
    }
}

extern "C" void kernel_launch(void* const* d_in, const int* in_sizes, int n_in,
                              void* d_out, int out_size, void* d_ws, size_t ws_size,
                              hipStream_t stream)
{
    const float* x      = (const float*)d_in[0];
    const int*   src    = (const int*)d_in[1];
    const int*   dst    = (const int*)d_in[2];
    const int*   etype  = (const int*)d_in[3];
    const float* coeff1 = (const float*)d_in[4];
    const float* basis1 = (const float*)d_in[5];
    const float* wloop1 = (const float*)d_in[6];
    const float* b1     = (const float*)d_in[7];
    const float* coeff2 = (const float*)d_in[8];
    const float* basis2 = (const float*)d_in[9];
    const float* wloop2 = (const float*)d_in[10];
    const float* b2     = (const float*)d_in[11];
    const float* wagg   = (const float*)d_in[12];
    const float* bagg   = (const float*)d_in[13];
    const float* wd1    = (const float*)d_in[14];
    const float* bd1    = (const float*)d_in[15];
    const float* wd2    = (const float*)d_in[16];
    const float* bd2    = (const float*)d_in[17];
    const float* wd3    = (const float*)d_in[18];
    const float* bd3    = (const float*)d_in[19];
    float* out = (float*)d_out;

    // ---- workspace layout ----
    char* p = (char*)d_ws;
    auto alloc = [&](size_t bytes) -> char* {
        char* q = p;
        p += (bytes + 255) & ~(size_t)255;
        return q;
    };
    ushort* Wt    = (ushort*)alloc(sizeof(ushort) * (size_t)2 * LSTRIDE);
    ushort* xb    = (ushort*)alloc(sizeof(ushort) * (size_t)NN * 128);
    ushort* hb    = (ushort*)alloc(sizeof(ushort) * (size_t)NN * 128);
    int*    curNR = (int*)alloc(sizeof(int) * (size_t)NN * RR);
    int*    bslot = (int*)alloc(sizeof(int) * (size_t)NN * RR * BCAP);
    float*  z     = (float*)alloc(sizeof(float) * NN);
    float*  y1    = (float*)alloc(sizeof(float) * 128);
    (void)ws_size;

    // ---- prep + bucket + convert ----
    k_prep<<<2048, 256, 0, stream>>>(coeff1, basis1, coeff2, basis2,
                                     wloop1, wloop2, Wt, curNR, y1);
    k_bucket<<<2048, 256, 0, stream>>>(src, dst, etype, curNR, bslot);
    k_cvt_x<<<2048, 256, 0, stream>>>(x, xb, (long)NN * 128 / 4);

    // ---- layer 1: x -> hb ----
    k_layer<<<NN / NT, 512, 0, stream>>>(
        xb, Wt, curNR, bslot, b1, hb, nullptr, nullptr, nullptr, 1);
    // ---- layer 2: hb -> z ----
    k_layer<<<NN / NT, 512, 0, stream>>>(
        hb, Wt + LSTRIDE, curNR, bslot, b2, nullptr, wagg, bagg, z, 2);

    // ---- head ----
    k_dense1<<<256, 256, 0, stream>>>(z, wd1, y1);
    k_final<<<1, 128, 0, stream>>>(y1, bd1, wd2, bd2, wd3, bd3, out);
}